// Round 2
// baseline (87.646 us; speedup 1.0000x reference)
//
#include <hip/hip_runtime.h>

// ConvAttention: B=2, C=64, H=32, W=32, S=16, KS=5
// x flat: b*1048576 + c*16384 + p*16 + t    (p = h*32+w)
//
// Math (harness-verified): softmax_t(sQ[s]+sK[t]+b2) == softmax_t(sK[t]).
// out[b,c,p,s] = w1v @ (sum_t attn[t] * x[:,t]) + b1v, identical over s.
// Pipeline (2 kernels): k_fgemm (per-block fused filter Ak = w2_K · w1_K in LDS,
// then u = Ak^T x), k_attn (gather + softmax + mix + proj).

__device__ __forceinline__ int reflect32(int i) {
    if (i < 0) i = -i;
    if (i >= 32) i = 62 - i;
    return i;
}

// K1: u[k][idx] = sum_c Ak[c][k] * x[c][idx]   (M=25, K=64, N=32768)
// Fuse phase folded in: every block computes Akp[c][k] = sum_cK w2K[cK][k]*w1K[cK][c]
// into LDS (1600 entries, ~3/thread, w2 on scalar path, w1 coalesced; 22KB L2-hot).
// The 8 per-thread x loads are issued BEFORE the fuse phase so HBM latency hides
// under the ~200 fuse FMAs. 8-way c-split across 8 waves; x read once; cross-wave
// reduce via LDS; Ak rows consumed as broadcast ds_read (uniform addr, conflict-free).
__global__ void __launch_bounds__(512) k_fgemm(const float* __restrict__ x,
                                               const float* __restrict__ w1,
                                               const float* __restrict__ w2,
                                               float* __restrict__ u) {
    __shared__ float akp[64 * 28];       // akp[c*28 + k], 7 KB
    __shared__ float part[8][25][64];    // 50 KB; writes/reads 2-way (free)
    int tid = threadIdx.x;
    int w   = __builtin_amdgcn_readfirstlane(tid >> 6);   // 0..7
    int l   = tid & 63;
    int idx = blockIdx.x * 64 + l;       // (b,p,t) flattened
    int b   = idx >> 14;
    int pt  = idx & 16383;
    const float* xp = x + b * 1048576 + pt;

    // --- issue x loads first (latency hides under fuse phase) ---
    float xv[8];
#pragma unroll
    for (int ci = 0; ci < 8; ++ci)
        xv[ci] = xp[(w * 8 + ci) * 16384];

    // --- fuse phase: Akp into LDS. e=k*64+cp: k wave-uniform -> w2 s_load,
    //     w1 coalesced 256B/wave. 1600 entries over 512 threads. ---
    for (int e = tid; e < 1600; e += 512) {
        int k  = e >> 6;                 // 0..24, wave-uniform
        int cp = e & 63;
        float acc = 0.f;
#pragma unroll 16
        for (int c = 0; c < 64; ++c)
            acc = fmaf(w2[(64 + c) * 25 + k], w1[(64 + c) * 64 + cp], acc);
        akp[cp * 28 + k] = acc;
    }
    __syncthreads();

    // --- gemm phase: 25-tap accumulate over this wave's 8 channels ---
    float acc[25];
#pragma unroll
    for (int k = 0; k < 25; ++k) acc[k] = 0.f;

#pragma unroll
    for (int ci = 0; ci < 8; ++ci) {
        const float* ak = akp + (w * 8 + ci) * 28;   // uniform -> broadcast ds_read
        float4 a0 = *(const float4*)(ak + 0);
        float4 a1 = *(const float4*)(ak + 4);
        float4 a2 = *(const float4*)(ak + 8);
        float4 a3 = *(const float4*)(ak + 12);
        float4 a4 = *(const float4*)(ak + 16);
        float4 a5 = *(const float4*)(ak + 20);
        float    a6 = ak[24];
        float xvc = xv[ci];
        acc[0]  = fmaf(a0.x, xvc, acc[0]);  acc[1]  = fmaf(a0.y, xvc, acc[1]);
        acc[2]  = fmaf(a0.z, xvc, acc[2]);  acc[3]  = fmaf(a0.w, xvc, acc[3]);
        acc[4]  = fmaf(a1.x, xvc, acc[4]);  acc[5]  = fmaf(a1.y, xvc, acc[5]);
        acc[6]  = fmaf(a1.z, xvc, acc[6]);  acc[7]  = fmaf(a1.w, xvc, acc[7]);
        acc[8]  = fmaf(a2.x, xvc, acc[8]);  acc[9]  = fmaf(a2.y, xvc, acc[9]);
        acc[10] = fmaf(a2.z, xvc, acc[10]); acc[11] = fmaf(a2.w, xvc, acc[11]);
        acc[12] = fmaf(a3.x, xvc, acc[12]); acc[13] = fmaf(a3.y, xvc, acc[13]);
        acc[14] = fmaf(a3.z, xvc, acc[14]); acc[15] = fmaf(a3.w, xvc, acc[15]);
        acc[16] = fmaf(a4.x, xvc, acc[16]); acc[17] = fmaf(a4.y, xvc, acc[17]);
        acc[18] = fmaf(a4.z, xvc, acc[18]); acc[19] = fmaf(a4.w, xvc, acc[19]);
        acc[20] = fmaf(a5.x, xvc, acc[20]); acc[21] = fmaf(a5.y, xvc, acc[21]);
        acc[22] = fmaf(a5.z, xvc, acc[22]); acc[23] = fmaf(a5.w, xvc, acc[23]);
        acc[24] = fmaf(a6,   xvc, acc[24]);
    }
#pragma unroll
    for (int k = 0; k < 25; ++k) part[w][k][l] = acc[k];
    __syncthreads();

    int base = blockIdx.x * 64;
    for (int e = tid; e < 1600; e += 512) {   // 1600 = 25 taps x 64 idx
        int k = e >> 6, l2 = e & 63;
        float s = part[0][k][l2];
#pragma unroll
        for (int ww = 1; ww < 8; ++ww) s += part[ww][k][l2];
        u[k * 32768 + base + l2] = s;         // coalesced 256B/wave
    }
}

// K2: sk gather + softmax_t + y-mix + w1v projection + store.
// u-gather loads hoisted ahead of LDS staging (latency hides under staging);
// wT staged with float4 loads.
__global__ void __launch_bounds__(256) k_attn(const float* __restrict__ x,
                                              const float* __restrict__ u,
                                              const float* __restrict__ w1,
                                              const float* __restrict__ b1,
                                              float* __restrict__ out) {
    __shared__ float wT[64 * 65];     // wT[i*65+cc] = w1v[cc][i]
    __shared__ float xs[4 * 1040];    // xs[pix*1040 + t*65 + cc]
    __shared__ float psk[4 * 64];
    __shared__ float sk_s[64];
    __shared__ float ysT[64 * 4];

    int tid = threadIdx.x;
    int g0  = blockIdx.x * 4;         // 4 pixels/block (same row: 4 | 32)
    int b   = g0 >> 10;
    int p0  = g0 & 1023;

    // --- phase A gather loads FIRST (u is L2-hot from k_fgemm), taps 7/7/7/4 ---
    int grp  = __builtin_amdgcn_readfirstlane(tid >> 6);   // wave-uniform
    int pixa = (tid >> 4) & 3;
    int ta   = tid & 15;
    int nk   = (grp == 3) ? 4 : 7;
    float ga[7];
    {
        int kk0 = grp * 7;
        int p   = p0 + pixa;
        int hh  = p >> 5, ww = p & 31;
        const float* ub = u + b * 16384 + ta;
#pragma unroll
        for (int q = 0; q < 7; ++q) {
            ga[q] = 0.f;
            if (q < nk) {                       // wave-uniform branch
                int k  = kk0 + q;
                int ky = k / 5, kx = k - ky * 5;
                int rh = reflect32(hh + ky - 2);
                int rw = reflect32(ww + kx - 2);
                ga[q] = ub[k * 32768 + (rh * 32 + rw) * 16];
            }
        }
    }

    // --- stage x tile, coalesced: 4 lanes x 16B = 64B contiguous per cc ---
    {
        int cc = tid >> 2, sub = tid & 3;
        const float* xbase = x + b * 1048576 + cc * 16384 + p0 * 16 + sub * 4;
#pragma unroll
        for (int pix = 0; pix < 4; ++pix) {
            float4 v = *(const float4*)(xbase + pix * 16);
            float* dst = xs + pix * 1040 + (4 * sub) * 65 + cc;
            dst[0] = v.x; dst[65] = v.y; dst[130] = v.z; dst[195] = v.w;
        }
    }
    // --- stage transposed projection weights (float4: 4 loads) ---
    {
        const float4* w1v4 = (const float4*)(w1 + 8192);
#pragma unroll
        for (int j = 0; j < 4; ++j) {
            int e4 = tid + j * 256;             // float4 index into w1v
            float4 v = w1v4[e4];
            int c  = e4 >> 4;                   // = (4*e4)>>6
            int i0 = (4 * e4) & 63;
            float* dst = wT + i0 * 65 + c;      // stride-65: conflict-free
            dst[0] = v.x; dst[65] = v.y; dst[130] = v.z; dst[195] = v.w;
        }
    }

    psk[grp * 64 + pixa * 16 + ta] =
        ga[0] + ga[1] + ga[2] + ga[3] + ga[4] + ga[5] + ga[6];
    __syncthreads();
    if (tid < 64)
        sk_s[tid] = psk[tid] + psk[64 + tid] + psk[128 + tid] + psk[192 + tid];
    __syncthreads();

    // --- softmax over t (wave-uniform broadcast) + y-mix from LDS ---
    {
        int pix = tid >> 6, cc = tid & 63;
        float sk[16];
#pragma unroll
        for (int t = 0; t < 16; ++t) sk[t] = sk_s[pix * 16 + t];
        float m = sk[0];
#pragma unroll
        for (int t = 1; t < 16; ++t) m = fmaxf(m, sk[t]);
        float e[16], ssum = 0.f;
#pragma unroll
        for (int t = 0; t < 16; ++t) { e[t] = __expf(sk[t] - m); ssum += e[t]; }
        float inv = 1.0f / ssum;

        const float* xr = xs + pix * 1040 + cc;
        float y = 0.f;
#pragma unroll
        for (int t = 0; t < 16; ++t) y = fmaf(e[t], xr[t * 65], y);
        ysT[cc * 4 + pix] = y * inv;
    }
    __syncthreads();

    // --- projection: o[pix][cc] = b1v[cc] + sum_i wT[i][cc]*y[pix][i] ---
    {
        int cc = tid >> 2, sub = tid & 3;
        float o0 = 0.f, o1 = 0.f, o2 = 0.f, o3 = 0.f;
#pragma unroll
        for (int ii = 0; ii < 16; ++ii) {
            int i = ii * 4 + sub;
            float wv = wT[i * 65 + cc];
            float4 yv = *(const float4*)(ysT + i * 4);
            o0 = fmaf(wv, yv.x, o0);
            o1 = fmaf(wv, yv.y, o1);
            o2 = fmaf(wv, yv.z, o2);
            o3 = fmaf(wv, yv.w, o3);
        }
        o0 += __shfl_xor(o0, 1); o0 += __shfl_xor(o0, 2);
        o1 += __shfl_xor(o1, 1); o1 += __shfl_xor(o1, 2);
        o2 += __shfl_xor(o2, 1); o2 += __shfl_xor(o2, 2);
        o3 += __shfl_xor(o3, 1); o3 += __shfl_xor(o3, 2);
        float bb = b1[128 + cc];
        o0 += bb; o1 += bb; o2 += bb; o3 += bb;

        float* ob = out + (size_t)(b * 64 + cc) * 16384 + p0 * 16 + sub * 4;
        *(float4*)(ob +  0) = make_float4(o0, o0, o0, o0);
        *(float4*)(ob + 16) = make_float4(o1, o1, o1, o1);
        *(float4*)(ob + 32) = make_float4(o2, o2, o2, o2);
        *(float4*)(ob + 48) = make_float4(o3, o3, o3, o3);
    }
}

extern "C" void kernel_launch(void* const* d_in, const int* in_sizes, int n_in,
                              void* d_out, int out_size, void* d_ws, size_t ws_size,
                              hipStream_t stream) {
    const float* x  = (const float*)d_in[0];
    const float* w1 = (const float*)d_in[1];
    const float* b1 = (const float*)d_in[2];
    const float* w2 = (const float*)d_in[3];
    // b2 (d_in[4]) cancels in the softmax over t — unused.
    float* out = (float*)d_out;
    float* u   = (float*)d_ws;    // 25*32768 floats

    k_fgemm<<<512, 512, 0, stream>>>(x, w1, w2, u);
    k_attn<<<512, 256, 0, stream>>>(x, u, w1, b1, out);
}

// Round 4
// 75.388 us; speedup vs baseline: 1.1626x; 1.1626x over previous
//
#include <hip/hip_runtime.h>

// ConvAttention: B=2, C=64, H=32, W=32, S=16, KS=5
// x flat: b*1048576 + c*16384 + p*16 + t    (p = h*32+w)
//
// Math (harness-verified): softmax_t(sQ[s]+sK[t]+b2) == softmax_t(sK[t]).
// out[b,c,p,s] = w1v @ (sum_t attn[t] * x[:,t]) + b1v, identical over s.
// Pipeline (3 kernels — R2 post-mortem: fusing k_fuse into k_gemm REGRESSED 11 µs;
// per-block redundant 64-deep serial chains at 2 blocks/CU cost more than a launch):
//   k_fuse (Ak = w2_K · w1_K, 25 blocks), k_gemm (u = Ak^T x), k_attn (gather+softmax+mix+proj).

typedef float f32x4 __attribute__((ext_vector_type(4)));  // native vec for nontemporal builtin

__device__ __forceinline__ int reflect32(int i) {
    if (i < 0) i = -i;
    if (i >= 32) i = 62 - i;
    return i;
}

// K1: Akp[cp*28 + k] = sum_c w2[(64+c)*25 + k] * w1[(64+c)*64 + cp]
// 4-way c-split across waves.
__global__ void __launch_bounds__(256) k_fuse(const float* __restrict__ w1,
                                              const float* __restrict__ w2,
                                              float* __restrict__ Akp) {
    __shared__ float part[4][64];
    int k  = blockIdx.x;                                        // 0..24
    int w  = __builtin_amdgcn_readfirstlane(threadIdx.x >> 6);  // 0..3
    int cp = threadIdx.x & 63;
    float acc = 0.f;
#pragma unroll
    for (int ci = 0; ci < 16; ++ci) {
        int c = w * 16 + ci;             // uniform -> w2 term is an s_load
        acc = fmaf(w2[(64 + c) * 25 + k], w1[(64 + c) * 64 + cp], acc);
    }
    part[w][cp] = acc;
    __syncthreads();
    if (threadIdx.x < 64)
        Akp[cp * 28 + k] = part[0][cp] + part[1][cp] + part[2][cp] + part[3][cp];
}

// K2: u[k][idx] = sum_c Ak[c][k] * x[c][idx]   (M=25, K=64, N=32768)
// 8-way c-split across 8 waves (512 thr/block): x read once, 16 waves/CU,
// 8 fully-unrolled independent loads per wave. Cross-wave reduce via LDS;
// Ak stays on the scalar path (uniform address -> s_load from K$).
__global__ void __launch_bounds__(512) k_gemm(const float* __restrict__ x,
                                              const float* __restrict__ Akp,
                                              float* __restrict__ u) {
    __shared__ float part[8][25][64];    // 50 KB; writes/reads 2-way (free)
    int tid = threadIdx.x;
    int w   = __builtin_amdgcn_readfirstlane(tid >> 6);   // 0..7
    int l   = tid & 63;
    int idx = blockIdx.x * 64 + l;       // (b,p,t) flattened
    int b   = idx >> 14;
    int pt  = idx & 16383;
    const float* xp = x + b * 1048576 + pt;

    float acc[25];
#pragma unroll
    for (int k = 0; k < 25; ++k) acc[k] = 0.f;

#pragma unroll
    for (int ci = 0; ci < 8; ++ci) {
        int c = w * 8 + ci;
        float xv = xp[c * 16384];
        const float* ak = Akp + c * 28;  // uniform -> s_load from K$
#pragma unroll
        for (int k = 0; k < 25; ++k)
            acc[k] = fmaf(ak[k], xv, acc[k]);
    }
#pragma unroll
    for (int k = 0; k < 25; ++k) part[w][k][l] = acc[k];
    __syncthreads();

    int base = blockIdx.x * 64;
    for (int e = tid; e < 1600; e += 512) {   // 1600 = 25 taps x 64 idx
        int k = e >> 6, l2 = e & 63;
        float s = part[0][k][l2];
#pragma unroll
        for (int ww = 1; ww < 8; ++ww) s += part[ww][k][l2];
        u[k * 32768 + base + l2] = s;         // coalesced 256B/wave
    }
}

// K3: sk gather + softmax_t + y-mix + w1v projection + store.
// u-gather loads hoisted ahead of LDS staging (latency hides under staging).
// Block j's x-tile == k_gemm block j's footprint (identical 512-block grids ->
// same XCD by dispatch order -> L2-hot re-read).
__global__ void __launch_bounds__(256) k_attn(const float* __restrict__ x,
                                              const float* __restrict__ u,
                                              const float* __restrict__ w1,
                                              const float* __restrict__ b1,
                                              float* __restrict__ out) {
    __shared__ float wT[64 * 65];     // wT[i*65+cc] = w1v[cc][i]
    __shared__ float xs[4 * 1040];    // xs[pix*1040 + t*65 + cc]
    __shared__ float psk[4 * 64];
    __shared__ float sk_s[64];
    __shared__ float ysT[64 * 4];

    int tid = threadIdx.x;
    int g0  = blockIdx.x * 4;         // 4 pixels/block (same row: 4 | 32)
    int b   = g0 >> 10;
    int p0  = g0 & 1023;

    // --- phase A gather loads FIRST (u is L2-hot from k_gemm), taps 7/7/7/4 ---
    int grp  = __builtin_amdgcn_readfirstlane(tid >> 6);   // wave-uniform
    int pixa = (tid >> 4) & 3;
    int ta   = tid & 15;
    int nk   = (grp == 3) ? 4 : 7;
    float ga[7];
    {
        int kk0 = grp * 7;
        int p   = p0 + pixa;
        int hh  = p >> 5, ww = p & 31;
        const float* ub = u + b * 16384 + ta;
#pragma unroll
        for (int q = 0; q < 7; ++q) {
            ga[q] = 0.f;
            if (q < nk) {                       // wave-uniform branch
                int k  = kk0 + q;
                int ky = k / 5, kx = k - ky * 5;
                int rh = reflect32(hh + ky - 2);
                int rw = reflect32(ww + kx - 2);
                ga[q] = ub[k * 32768 + (rh * 32 + rw) * 16];
            }
        }
    }

    // --- stage x tile, coalesced: 4 lanes x 16B = 64B contiguous per cc ---
    {
        int cc = tid >> 2, sub = tid & 3;
        const float* xbase = x + b * 1048576 + cc * 16384 + p0 * 16 + sub * 4;
#pragma unroll
        for (int pix = 0; pix < 4; ++pix) {
            float4 v = *(const float4*)(xbase + pix * 16);
            float* dst = xs + pix * 1040 + (4 * sub) * 65 + cc;
            dst[0] = v.x; dst[65] = v.y; dst[130] = v.z; dst[195] = v.w;
        }
    }
    // --- stage transposed projection weights (float4: 4 loads; L1-hot) ---
    {
        const float4* w1v4 = (const float4*)(w1 + 8192);
#pragma unroll
        for (int j = 0; j < 4; ++j) {
            int e4 = tid + j * 256;             // float4 index into w1v
            float4 v = w1v4[e4];
            int c  = e4 >> 4;                   // = (4*e4)>>6
            int i0 = (4 * e4) & 63;
            float* dst = wT + i0 * 65 + c;      // stride-65: conflict-free
            dst[0] = v.x; dst[65] = v.y; dst[130] = v.z; dst[195] = v.w;
        }
    }

    psk[grp * 64 + pixa * 16 + ta] =
        ga[0] + ga[1] + ga[2] + ga[3] + ga[4] + ga[5] + ga[6];
    __syncthreads();
    if (tid < 64)
        sk_s[tid] = psk[tid] + psk[64 + tid] + psk[128 + tid] + psk[192 + tid];
    __syncthreads();

    // --- softmax over t (wave-uniform broadcast) + y-mix from LDS ---
    {
        int pix = tid >> 6, cc = tid & 63;
        float sk[16];
#pragma unroll
        for (int t = 0; t < 16; ++t) sk[t] = sk_s[pix * 16 + t];
        float m = sk[0];
#pragma unroll
        for (int t = 1; t < 16; ++t) m = fmaxf(m, sk[t]);
        float e[16], ssum = 0.f;
#pragma unroll
        for (int t = 0; t < 16; ++t) { e[t] = __expf(sk[t] - m); ssum += e[t]; }
        float inv = 1.0f / ssum;

        const float* xr = xs + pix * 1040 + cc;
        float y = 0.f;
#pragma unroll
        for (int t = 0; t < 16; ++t) y = fmaf(e[t], xr[t * 65], y);
        ysT[cc * 4 + pix] = y * inv;
    }
    __syncthreads();

    // --- projection: o[pix][cc] = b1v[cc] + sum_i wT[i][cc]*y[pix][i] ---
    {
        int cc = tid >> 2, sub = tid & 3;
        float o0 = 0.f, o1 = 0.f, o2 = 0.f, o3 = 0.f;
#pragma unroll
        for (int ii = 0; ii < 16; ++ii) {
            int i = ii * 4 + sub;
            float wv = wT[i * 65 + cc];
            float4 yv = *(const float4*)(ysT + i * 4);
            o0 = fmaf(wv, yv.x, o0);
            o1 = fmaf(wv, yv.y, o1);
            o2 = fmaf(wv, yv.z, o2);
            o3 = fmaf(wv, yv.w, o3);
        }
        o0 += __shfl_xor(o0, 1); o0 += __shfl_xor(o0, 2);
        o1 += __shfl_xor(o1, 1); o1 += __shfl_xor(o1, 2);
        o2 += __shfl_xor(o2, 1); o2 += __shfl_xor(o2, 2);
        o3 += __shfl_xor(o3, 1); o3 += __shfl_xor(o3, 2);
        float bb = b1[128 + cc];
        o0 += bb; o1 += bb; o2 += bb; o3 += bb;

        // nontemporal: out (8.4 MB) is never re-read — don't evict x/u from L2.
        // (native ext_vector type: __builtin_nontemporal_store rejects HIP float4)
        float* ob = out + (size_t)(b * 64 + cc) * 16384 + p0 * 16 + sub * 4;
        f32x4 v0 = {o0, o0, o0, o0};
        f32x4 v1 = {o1, o1, o1, o1};
        f32x4 v2 = {o2, o2, o2, o2};
        f32x4 v3 = {o3, o3, o3, o3};
        __builtin_nontemporal_store(v0, (f32x4*)(ob +  0));
        __builtin_nontemporal_store(v1, (f32x4*)(ob + 16));
        __builtin_nontemporal_store(v2, (f32x4*)(ob + 32));
        __builtin_nontemporal_store(v3, (f32x4*)(ob + 48));
    }
}

extern "C" void kernel_launch(void* const* d_in, const int* in_sizes, int n_in,
                              void* d_out, int out_size, void* d_ws, size_t ws_size,
                              hipStream_t stream) {
    const float* x  = (const float*)d_in[0];
    const float* w1 = (const float*)d_in[1];
    const float* b1 = (const float*)d_in[2];
    const float* w2 = (const float*)d_in[3];
    // b2 (d_in[4]) cancels in the softmax over t — unused.
    float* out = (float*)d_out;
    float* ws  = (float*)d_ws;

    float* Akp = ws;          // 64*28 floats
    float* u   = ws + 2048;   // 25*32768 floats

    k_fuse<<<25, 256, 0, stream>>>(w1, w2, Akp);
    k_gemm<<<512, 512, 0, stream>>>(x, Akp, u);
    k_attn<<<512, 256, 0, stream>>>(x, u, w1, b1, out);
}